// Round 4
// baseline (805.223 us; speedup 1.0000x reference)
//
#include <hip/hip_runtime.h>
#include <hip/hip_bf16.h>

typedef unsigned short u16;
typedef unsigned int u32;

#define NN 10000
#define EE 320000

typedef __attribute__((ext_vector_type(8))) short short8;
typedef __attribute__((ext_vector_type(4))) float f32x4;

__device__ __forceinline__ u16 f2bfu(float f) {
    u32 x = __float_as_uint(f);
    x += 0x7FFFu + ((x >> 16) & 1u);   // round-to-nearest-even
    return (u16)(x >> 16);
}
__device__ __forceinline__ void ld4f(const float* p, float* o) {
    float4 v = *(const float4*)p; o[0] = v.x; o[1] = v.y; o[2] = v.z; o[3] = v.w;
}

// ---------------- CSR build ----------------
__global__ void k_hist(const int* __restrict__ dst, int* __restrict__ cnt) {
    int e = blockIdx.x * 256 + threadIdx.x;
    if (e < EE) atomicAdd(&cnt[dst[e]], 1);
}

__global__ void k_dinv(const int* __restrict__ cnt, float* __restrict__ dinv) {
    int n = blockIdx.x * 256 + threadIdx.x;
    if (n < NN) dinv[n] = 1.f / sqrtf((float)(cnt[n] + 1));  // +1 self loop; deg>=1 always
}

__global__ void k_scan(const int* __restrict__ cnt, int* __restrict__ rowptr) {
    __shared__ int sh[1024];
    int t = threadIdx.x;
    int base = t * 10;
    int loc[10];
    int s = 0;
    #pragma unroll
    for (int i = 0; i < 10; i++) {
        int idx = base + i;
        int v = (idx < NN) ? cnt[idx] : 0;
        loc[i] = s; s += v;
    }
    sh[t] = s;
    __syncthreads();
    for (int off = 1; off < 1024; off <<= 1) {
        int v = (t >= off) ? sh[t - off] : 0;
        __syncthreads();
        sh[t] += v;
        __syncthreads();
    }
    int ex = sh[t] - s;   // exclusive base for this thread's chunk
    #pragma unroll
    for (int i = 0; i < 10; i++) {
        int idx = base + i;
        if (idx < NN) rowptr[idx] = ex + loc[i];
    }
    if (t == 0) rowptr[NN] = EE;
}

__global__ void k_scatter(const int* __restrict__ src, const int* __restrict__ dst,
                          const int* __restrict__ rowptr, int* __restrict__ fill,
                          int* __restrict__ csr) {
    int e = blockIdx.x * 256 + threadIdx.x;
    if (e < EE) {
        int d = dst[e];
        int pos = rowptr[d] + atomicAdd(&fill[d], 1);
        csr[pos] = src[e];
    }
}

// ---------------- generic dense layer: out[N,M] = act(A[N,K] @ W[K,M] + b) ----------------
// wave handles 4 rows; lane covers cols {lane + 64*j}
template <int K, int M, bool RELU, bool BIAS>
__global__ __launch_bounds__(256) void k_linear(const float* __restrict__ A, const float* __restrict__ W,
                                                const float* __restrict__ Bb, float* __restrict__ out) {
    constexpr int MC = M / 64;
    int wid = (blockIdx.x * blockDim.x + threadIdx.x) >> 6;
    int lane = threadIdx.x & 63;
    int row0 = wid * 4;
    if (row0 >= NN) return;
    float acc[4][MC];
    #pragma unroll
    for (int i = 0; i < 4; i++)
        #pragma unroll
        for (int j = 0; j < MC; j++) acc[i][j] = 0.f;
    for (int k = 0; k < K; k += 4) {
        float a[4][4];
        #pragma unroll
        for (int i = 0; i < 4; i++) ld4f(A + (size_t)(row0 + i) * K + k, a[i]);
        #pragma unroll
        for (int kk = 0; kk < 4; kk++) {
            float wv[MC];
            #pragma unroll
            for (int j = 0; j < MC; j++) wv[j] = W[(size_t)(k + kk) * M + j * 64 + lane];
            #pragma unroll
            for (int i = 0; i < 4; i++)
                #pragma unroll
                for (int j = 0; j < MC; j++) acc[i][j] += a[i][kk] * wv[j];
        }
    }
    #pragma unroll
    for (int i = 0; i < 4; i++) {
        int r = row0 + i;
        #pragma unroll
        for (int j = 0; j < MC; j++) {
            float v = acc[i][j];
            if constexpr (BIAS) v += Bb[j * 64 + lane];
            if constexpr (RELU) v = fmaxf(v, 0.f);
            out[(size_t)r * M + j * 64 + lane] = v;
        }
    }
}

// ---------------- GCN aggregation ----------------
__global__ __launch_bounds__(256) void k_gcn_agg(const float* __restrict__ h0, const int* __restrict__ rowptr,
                                                 const int* __restrict__ csr, const float* __restrict__ dinv,
                                                 const float* __restrict__ bias, float* __restrict__ h1) {
    int node = (blockIdx.x * blockDim.x + threadIdx.x) >> 6;
    int lane = threadIdx.x & 63;
    if (node >= NN) return;
    float di = dinv[node];
    const float* hn = h0 + (size_t)node * 128;
    float acc0 = hn[lane] * di * di;        // self loop
    float acc1 = hn[64 + lane] * di * di;
    int st = rowptr[node], en = rowptr[node + 1];
    for (int p = st; p < en; p++) {
        int s = csr[p];
        float w = dinv[s] * di;
        const float* hs = h0 + (size_t)s * 128;
        acc0 += hs[lane] * w;
        acc1 += hs[64 + lane] * w;
    }
    acc0 += bias[lane];
    acc1 += bias[64 + lane];
    h1[(size_t)node * 128 + lane] = fmaxf(acc0, 0.f);
    h1[(size_t)node * 128 + 64 + lane] = fmaxf(acc1, 0.f);
}

// ---------------- GAT attention scores a_src/a_dst [N,4] ----------------
__global__ __launch_bounds__(256) void k_gat_scores(const float* __restrict__ g, const float* __restrict__ att_s,
                                                    const float* __restrict__ att_d, float* __restrict__ a_src,
                                                    float* __restrict__ a_dst) {
    int node = (blockIdx.x * blockDim.x + threadIdx.x) >> 6;
    int lane = threadIdx.x & 63;
    if (node >= NN) return;
    const float* gp = g + (size_t)node * 512 + lane * 8;
    float gv[8];
    ld4f(gp, gv); ld4f(gp + 4, gv + 4);
    float sv[8], dv[8];
    ld4f(att_s + lane * 8, sv); ld4f(att_s + lane * 8 + 4, sv + 4);
    ld4f(att_d + lane * 8, dv); ld4f(att_d + lane * 8 + 4, dv + 4);
    float ps = 0.f, pd = 0.f;
    #pragma unroll
    for (int i = 0; i < 8; i++) { ps += gv[i] * sv[i]; pd += gv[i] * dv[i]; }
    // reduce within 16-lane groups (one head per group)
    for (int off = 1; off < 16; off <<= 1) {
        ps += __shfl_xor(ps, off, 64);
        pd += __shfl_xor(pd, off, 64);
    }
    if ((lane & 15) == 0) {
        int h = lane >> 4;
        a_src[node * 4 + h] = ps;
        a_dst[node * 4 + h] = pd;
    }
}

// ---------------- GAT softmax over incoming edges ----------------
__global__ __launch_bounds__(256) void k_gat_softmax(const int* __restrict__ rowptr, const int* __restrict__ csr,
                                                     const float* __restrict__ a_src, const float* __restrict__ a_dst,
                                                     float* __restrict__ alpha, float* __restrict__ selfalpha) {
    int node = (blockIdx.x * blockDim.x + threadIdx.x) >> 6;
    int lane = threadIdx.x & 63;
    if (node >= NN) return;
    float ad[4], asn[4];
    ld4f(a_dst + node * 4, ad);
    ld4f(a_src + node * 4, asn);
    float es[4], m[4];
    #pragma unroll
    for (int h = 0; h < 4; h++) {
        float e = asn[h] + ad[h];
        es[h] = e > 0.f ? e : 0.2f * e;   // self-loop score
        m[h] = es[h];                      // max is idempotent: every lane can seed with it
    }
    int st = rowptr[node], en = rowptr[node + 1];
    for (int p = st + lane; p < en; p += 64) {
        int s = csr[p];
        float as[4]; ld4f(a_src + s * 4, as);
        #pragma unroll
        for (int h = 0; h < 4; h++) {
            float e = as[h] + ad[h];
            e = e > 0.f ? e : 0.2f * e;
            m[h] = fmaxf(m[h], e);
        }
    }
    #pragma unroll
    for (int h = 0; h < 4; h++)
        for (int off = 1; off < 64; off <<= 1) m[h] = fmaxf(m[h], __shfl_xor(m[h], off, 64));
    float den[4];
    #pragma unroll
    for (int h = 0; h < 4; h++) den[h] = (lane == 0) ? __expf(es[h] - m[h]) : 0.f;  // self counted once
    for (int p = st + lane; p < en; p += 64) {
        int s = csr[p];
        float as[4]; ld4f(a_src + s * 4, as);
        #pragma unroll
        for (int h = 0; h < 4; h++) {
            float e = as[h] + ad[h];
            e = e > 0.f ? e : 0.2f * e;
            den[h] += __expf(e - m[h]);
        }
    }
    #pragma unroll
    for (int h = 0; h < 4; h++)
        for (int off = 1; off < 64; off <<= 1) den[h] += __shfl_xor(den[h], off, 64);
    float inv[4];
    #pragma unroll
    for (int h = 0; h < 4; h++) inv[h] = 1.f / den[h];
    for (int p = st + lane; p < en; p += 64) {
        int s = csr[p];
        float as[4]; ld4f(a_src + s * 4, as);
        float4 al;
        float av[4];
        #pragma unroll
        for (int h = 0; h < 4; h++) {
            float e = as[h] + ad[h];
            e = e > 0.f ? e : 0.2f * e;
            av[h] = __expf(e - m[h]) * inv[h];
        }
        al.x = av[0]; al.y = av[1]; al.z = av[2]; al.w = av[3];
        *(float4*)(alpha + (size_t)p * 4) = al;
    }
    if (lane == 0) {
        float4 sa;
        sa.x = __expf(es[0] - m[0]) * inv[0];
        sa.y = __expf(es[1] - m[1]) * inv[1];
        sa.z = __expf(es[2] - m[2]) * inv[2];
        sa.w = __expf(es[3] - m[3]) * inv[3];
        *(float4*)(selfalpha + (size_t)node * 4) = sa;
    }
}

// ---------------- GAT aggregation (mean over heads) ----------------
__global__ __launch_bounds__(256) void k_gat_agg(const float* __restrict__ g, const int* __restrict__ rowptr,
                                                 const int* __restrict__ csr, const float* __restrict__ alpha,
                                                 const float* __restrict__ selfalpha, const float* __restrict__ bias,
                                                 float* __restrict__ h2) {
    int node = (blockIdx.x * blockDim.x + threadIdx.x) >> 6;
    int lane = threadIdx.x & 63;
    if (node >= NN) return;
    float sa[4];
    ld4f(selfalpha + (size_t)node * 4, sa);
    const float* gn = g + (size_t)node * 512;
    float acc0 = 0.f, acc1 = 0.f;
    #pragma unroll
    for (int h = 0; h < 4; h++) {
        acc0 += sa[h] * gn[h * 128 + lane];
        acc1 += sa[h] * gn[h * 128 + 64 + lane];
    }
    int st = rowptr[node], en = rowptr[node + 1];
    for (int p = st; p < en; p++) {
        int s = csr[p];
        float al[4];
        ld4f(alpha + (size_t)p * 4, al);
        const float* gs = g + (size_t)s * 512;
        #pragma unroll
        for (int h = 0; h < 4; h++) {
            acc0 += al[h] * gs[h * 128 + lane];
            acc1 += al[h] * gs[h * 128 + 64 + lane];
        }
    }
    acc0 = fmaxf(acc0 * 0.25f + bias[lane], 0.f);
    acc1 = fmaxf(acc1 * 0.25f + bias[64 + lane], 0.f);
    h2[(size_t)node * 128 + lane] = acc0;
    h2[(size_t)node * 128 + 64 + lane] = acc1;
}

// ---------------- mu head: fp32 mu written directly to out_mu ----------------
__global__ __launch_bounds__(256) void k_mu(const float* __restrict__ A, const float* __restrict__ W,
                                            const float* __restrict__ Bb, float* __restrict__ mu_out) {
    int wid = (blockIdx.x * blockDim.x + threadIdx.x) >> 6;
    int lane = threadIdx.x & 63;
    int row0 = wid * 4;
    if (row0 >= NN) return;
    float acc[4] = {0.f, 0.f, 0.f, 0.f};
    for (int k = 0; k < 128; k += 4) {
        float a[4][4];
        #pragma unroll
        for (int i = 0; i < 4; i++) ld4f(A + (size_t)(row0 + i) * 128 + k, a[i]);
        #pragma unroll
        for (int kk = 0; kk < 4; kk++) {
            float wv = W[(k + kk) * 64 + lane];
            #pragma unroll
            for (int i = 0; i < 4; i++) acc[i] += a[i][kk] * wv;
        }
    }
    float b = Bb[lane];
    #pragma unroll
    for (int i = 0; i < 4; i++)
        mu_out[(size_t)(row0 + i) * 64 + lane] = acc[i] + b;
}

// ---------------- logvar head + reparameterize (lv -> out_lv fp32, z -> ws) ----------------
__global__ __launch_bounds__(256) void k_lv(const float* __restrict__ A, const float* __restrict__ W,
                                            const float* __restrict__ Bb, const float* __restrict__ mu,
                                            const float* __restrict__ eps, float* __restrict__ z,
                                            float* __restrict__ lv_out) {
    int wid = (blockIdx.x * blockDim.x + threadIdx.x) >> 6;
    int lane = threadIdx.x & 63;
    int row0 = wid * 4;
    if (row0 >= NN) return;
    float acc[4] = {0.f, 0.f, 0.f, 0.f};
    for (int k = 0; k < 128; k += 4) {
        float a[4][4];
        #pragma unroll
        for (int i = 0; i < 4; i++) ld4f(A + (size_t)(row0 + i) * 128 + k, a[i]);
        #pragma unroll
        for (int kk = 0; kk < 4; kk++) {
            float wv = W[(k + kk) * 64 + lane];
            #pragma unroll
            for (int i = 0; i < 4; i++) acc[i] += a[i][kk] * wv;
        }
    }
    float b = Bb[lane];
    #pragma unroll
    for (int i = 0; i < 4; i++) {
        size_t idx = (size_t)(row0 + i) * 64 + lane;
        float lv = acc[i] + b;
        lv_out[idx] = lv;                              // unclipped logvar is the output
        float c = fminf(fmaxf(lv, -10.f), 10.f);
        z[idx] = mu[idx] + eps[idx] * __expf(0.5f * c);
    }
}

// ---------------- decoder layer 2 + residual -> bf16 d ----------------
__global__ __launch_bounds__(256) void k_dec2(const float* __restrict__ A, const float* __restrict__ W,
                                              const float* __restrict__ Bb, const float* __restrict__ z,
                                              u16* __restrict__ dbf) {
    int wid = (blockIdx.x * blockDim.x + threadIdx.x) >> 6;
    int lane = threadIdx.x & 63;
    int row0 = wid * 4;
    if (row0 >= NN) return;
    float acc[4] = {0.f, 0.f, 0.f, 0.f};
    for (int k = 0; k < 128; k += 4) {
        float a[4][4];
        #pragma unroll
        for (int i = 0; i < 4; i++) ld4f(A + (size_t)(row0 + i) * 128 + k, a[i]);
        #pragma unroll
        for (int kk = 0; kk < 4; kk++) {
            float wv = W[(k + kk) * 64 + lane];
            #pragma unroll
            for (int i = 0; i < 4; i++) acc[i] += a[i][kk] * wv;
        }
    }
    float b = Bb[lane];
    #pragma unroll
    for (int i = 0; i < 4; i++) {
        size_t idx = (size_t)(row0 + i) * 64 + lane;
        dbf[idx] = f2bfu(acc[i] + b + z[idx]);
    }
}

// ---------------- logits = d @ d^T via MFMA bf16, fp32 output ----------------
// block 256 threads = 4 waves; block computes a 128x128 output tile; each wave 64x64.
__global__ __launch_bounds__(256) void k_logits(const u16* __restrict__ dbf, float* __restrict__ out) {
    __shared__ float tile[64][132];   // half-tile (64 rows), +4 pad keeps float4 alignment
    int tid = threadIdx.x;
    int wave = tid >> 6;
    int lane = tid & 63;
    int l15 = lane & 15, quad = lane >> 4;
    int rowhalf = wave >> 1;          // which 64-row half this wave computes
    int i0 = blockIdx.y * 128 + rowhalf * 64;
    int j0 = blockIdx.x * 128 + (wave & 1) * 64;

    f32x4 acc[4][4];
    #pragma unroll
    for (int r = 0; r < 4; r++)
        #pragma unroll
        for (int c = 0; c < 4; c++) acc[r][c] = (f32x4){0.f, 0.f, 0.f, 0.f};

    #pragma unroll
    for (int ks = 0; ks < 64; ks += 32) {
        short8 a[4], b[4];
        #pragma unroll
        for (int r = 0; r < 4; r++) {
            int row = i0 + r * 16 + l15;
            if (row < NN) a[r] = *(const short8*)(dbf + (size_t)row * 64 + ks + quad * 8);
            else a[r] = (short8){0, 0, 0, 0, 0, 0, 0, 0};
        }
        #pragma unroll
        for (int c = 0; c < 4; c++) {
            int row = j0 + c * 16 + l15;
            if (row < NN) b[c] = *(const short8*)(dbf + (size_t)row * 64 + ks + quad * 8);
            else b[c] = (short8){0, 0, 0, 0, 0, 0, 0, 0};
        }
        #pragma unroll
        for (int r = 0; r < 4; r++)
            #pragma unroll
            for (int c = 0; c < 4; c++)
                acc[r][c] = __builtin_amdgcn_mfma_f32_16x16x32_bf16(a[r], b[c], acc[r][c], 0, 0, 0);
    }

    // two chunks of 64 rows: fragments -> LDS (fp32) -> coalesced float4 stores
    int lc0 = (wave & 1) * 64;
    #pragma unroll
    for (int chunk = 0; chunk < 2; chunk++) {
        if (rowhalf == chunk) {
            // C layout: row_in_16 = quad*4 + v, col_in_16 = l15
            #pragma unroll
            for (int r = 0; r < 4; r++)
                #pragma unroll
                for (int c = 0; c < 4; c++)
                    #pragma unroll
                    for (int v = 0; v < 4; v++)
                        tile[r * 16 + quad * 4 + v][lc0 + c * 16 + l15] = acc[r][c][v];
        }
        __syncthreads();
        // 64 rows x 128 cols fp32 = 2048 float4 chunks; 8 per thread
        #pragma unroll
        for (int it = 0; it < 8; it++) {
            int idx = it * 256 + tid;
            int row = idx >> 5, ch = idx & 31;
            int rg = blockIdx.y * 128 + chunk * 64 + row;
            int cg = blockIdx.x * 128 + ch * 4;
            if (rg < NN && cg < NN) {   // NN % 4 == 0: chunk never straddles the edge
                float4 v = *(const float4*)&tile[row][ch * 4];
                *(float4*)(out + (size_t)rg * NN + cg) = v;
            }
        }
        __syncthreads();
    }
}

// ---------------- host ----------------
extern "C" void kernel_launch(void* const* d_in, const int* in_sizes, int n_in,
                              void* d_out, int out_size, void* d_ws, size_t ws_size,
                              hipStream_t stream) {
    const float* x      = (const float*)d_in[0];
    const int*   ei     = (const int*)d_in[1];
    const float* eps    = (const float*)d_in[2];
    const float* gcn_w  = (const float*)d_in[3];
    const float* gcn_b  = (const float*)d_in[4];
    const float* gat_w  = (const float*)d_in[5];
    const float* att_s  = (const float*)d_in[6];
    const float* att_d  = (const float*)d_in[7];
    const float* gat_b  = (const float*)d_in[8];
    const float* mlp_w1 = (const float*)d_in[9];
    const float* mlp_b1 = (const float*)d_in[10];
    const float* mlp_w2 = (const float*)d_in[11];
    const float* mlp_b2 = (const float*)d_in[12];
    const float* mu_w   = (const float*)d_in[13];
    const float* mu_b   = (const float*)d_in[14];
    const float* lv_w   = (const float*)d_in[15];
    const float* lv_b   = (const float*)d_in[16];
    const float* dec_w1 = (const float*)d_in[17];
    const float* dec_b1 = (const float*)d_in[18];
    const float* dec_w2 = (const float*)d_in[19];
    const float* dec_b2 = (const float*)d_in[20];

    float* out    = (float*)d_out;              // fp32 outputs, concatenated
    float* out_mu = out + (size_t)NN * NN;
    float* out_lv = out_mu + (size_t)NN * 64;

    char* ws = (char*)d_ws;
    size_t off = 0;
    auto alloc = [&](size_t bytes) -> void* {
        void* p = ws + off;
        off += (bytes + 255) & ~(size_t)255;
        return p;
    };
    int*   cnt       = (int*)alloc(NN * 4);
    int*   fill      = (int*)alloc(NN * 4);
    int*   rowptr    = (int*)alloc((NN + 1) * 4);
    int*   csr       = (int*)alloc(EE * 4);
    float* dinv      = (float*)alloc(NN * 4);
    float* a_src     = (float*)alloc(NN * 4 * 4);
    float* a_dst     = (float*)alloc(NN * 4 * 4);
    float* selfalpha = (float*)alloc(NN * 4 * 4);
    float* z         = (float*)alloc((size_t)NN * 64 * 4);
    float* h2        = (float*)alloc((size_t)NN * 128 * 4);
    float* bufA      = (float*)alloc((size_t)NN * 128 * 4);   // h0, later m1
    float* bufB      = (float*)alloc((size_t)NN * 128 * 4);   // h1, later m2
    float* bufC      = (float*)alloc((size_t)NN * 512 * 4);   // g, later t1
    float* bufD      = (float*)alloc((size_t)EE * 4 * 4);     // alpha, later dbf

    float* h0    = bufA;
    float* h1    = bufB;
    float* g     = bufC;
    float* alpha = bufD;
    float* m1    = bufA;   // h0 dead after k_gcn_agg
    float* m2    = bufB;   // h1 dead after GAT linear
    float* t1    = bufC;   // g dead after k_gat_agg
    u16*   dbf   = (u16*)bufD;  // alpha dead after k_gat_agg

    const int* src = ei;
    const int* dst = ei + EE;

    hipMemsetAsync(cnt, 0, NN * 4, stream);
    hipMemsetAsync(fill, 0, NN * 4, stream);

    k_hist<<<(EE + 255) / 256, 256, 0, stream>>>(dst, cnt);
    k_dinv<<<(NN + 255) / 256, 256, 0, stream>>>(cnt, dinv);
    k_scan<<<1, 1024, 0, stream>>>(cnt, rowptr);
    k_scatter<<<(EE + 255) / 256, 256, 0, stream>>>(src, dst, rowptr, fill, csr);

    // GCN
    k_linear<128, 128, false, false><<<625, 256, 0, stream>>>(x, gcn_w, nullptr, h0);
    k_gcn_agg<<<2500, 256, 0, stream>>>(h0, rowptr, csr, dinv, gcn_b, h1);

    // GAT
    k_linear<128, 512, false, false><<<625, 256, 0, stream>>>(h1, gat_w, nullptr, g);
    k_gat_scores<<<2500, 256, 0, stream>>>(g, att_s, att_d, a_src, a_dst);
    k_gat_softmax<<<2500, 256, 0, stream>>>(rowptr, csr, a_src, a_dst, alpha, selfalpha);
    k_gat_agg<<<2500, 256, 0, stream>>>(g, rowptr, csr, alpha, selfalpha, gat_b, h2);

    // MLP encoder
    k_linear<128, 128, true, true><<<625, 256, 0, stream>>>(h2, mlp_w1, mlp_b1, m1);
    k_linear<128, 128, true, true><<<625, 256, 0, stream>>>(m1, mlp_w2, mlp_b2, m2);
    k_mu<<<625, 256, 0, stream>>>(m2, mu_w, mu_b, out_mu);
    k_lv<<<625, 256, 0, stream>>>(m2, lv_w, lv_b, out_mu, eps, z, out_lv);

    // decoder
    k_linear<64, 128, true, true><<<625, 256, 0, stream>>>(z, dec_w1, dec_b1, t1);
    k_dec2<<<625, 256, 0, stream>>>(t1, dec_w2, dec_b2, z, dbf);

    // logits = d @ d^T (fp32 out)
    dim3 lgrid((NN + 127) / 128, (NN + 127) / 128);
    k_logits<<<lgrid, 256, 0, stream>>>(dbf, out);
}